// Round 9
// baseline (137.443 us; speedup 1.0000x reference)
//
#include <hip/hip_runtime.h>
#include <hip/hip_bf16.h>
#include <math.h>

#define N 4096
#define D 256
#define NCAM 8
#define SCALEF 10.0f
#define EPSF 1e-5f
#define MARGIN_INTRA 40.0f
#define MARGIN_INTER 6.0f
// reference excludes sorted_intra[0:4] = diagonal + top-3 non-diag, sorted_inter[0:6]
#define LI 3
#define LX 6
#define NCHUNK 16   // j-chunks of 256
#define NSTRIP 64   // i-strips of 64 -> 1024 blocks
#define PPARTS (NCHUNK * 2)  // partial per (chunk, wr)

#define LOG2EF 1.44269504f
#define LN2F 0.69314718f

typedef unsigned short ushort_t;
typedef __attribute__((ext_vector_type(8))) short short8;
typedef __attribute__((ext_vector_type(4))) float floatx4;

__device__ __forceinline__ ushort_t f2bf(float x) {
    __hip_bfloat16 h = __float2bfloat16(x);
    return *reinterpret_cast<ushort_t*>(&h);
}
__device__ __forceinline__ float bf2f(ushort_t u) {
    __hip_bfloat16 h = *reinterpret_cast<__hip_bfloat16*>(&u);
    return __bfloat162float(h);
}

__device__ __forceinline__ float fast_exp2(float x) {
#if __has_builtin(__builtin_amdgcn_exp2f)
    return __builtin_amdgcn_exp2f(x);
#else
    return exp2f(x);
#endif
}

// Insert v into descending-sorted list t[0..L-1], keep top L.
// t0' = max(t0,v); tq' = med3(t[q-1], t[q], v)  -> L ops, depth-1 chain.
template <int L>
__device__ __forceinline__ void insert_desc(float (&t)[L], float v) {
    float top = fmaxf(t[0], v);
#pragma unroll
    for (int q = L - 1; q >= 1; --q)
        t[q] = __builtin_amdgcn_fmed3f(t[q - 1], t[q], v);
    t[0] = top;
}

// ---------------- Kernel 0: counting sort of rows by camid ----------------
// Loss is permutation-invariant (per-row loss summed over rows; each row's
// distance SET is unchanged); sorting makes each camera's columns one
// contiguous range -> wave-uniform intra/inter classification in the fused
// epilogue. Within-camera order is arbitrary (only reorders fp sums).
__global__ __launch_bounds__(256) void sort_kernel(const int* __restrict__ camid,
                                                   int* __restrict__ perm,
                                                   int* __restrict__ sortedCam,
                                                   int* __restrict__ camLoC,
                                                   int* __restrict__ camHiC) {
    __shared__ int hist[NCAM], cursor[NCAM];
    int tid = threadIdx.x;
    if (tid < NCAM) hist[tid] = 0;
    __syncthreads();
    int ids[16];
#pragma unroll
    for (int q = 0; q < 16; ++q) {
        ids[q] = camid[tid * 16 + q];
        atomicAdd(&hist[ids[q]], 1);
    }
    __syncthreads();
    if (tid == 0) {
        int acc = 0;
        for (int c = 0; c < NCAM; ++c) {
            cursor[c] = acc;
            camLoC[c] = acc;
            acc += hist[c];
            camHiC[c] = acc;
        }
    }
    __syncthreads();
#pragma unroll
    for (int q = 0; q < 16; ++q) {
        int o = tid * 16 + q;
        int pos = atomicAdd(&cursor[ids[q]], 1);
        perm[pos] = o;
        sortedCam[pos] = ids[q];
    }
}

// ---------------- Kernel 1: per-row sq, R, bf16 hi/lo split (gathered) ----------------
__global__ __launch_bounds__(64) void prep_kernel(const float* __restrict__ F,
                                                  const int* __restrict__ perm,
                                                  ushort_t* __restrict__ Fhi,
                                                  ushort_t* __restrict__ Flo,
                                                  float* __restrict__ sq,
                                                  float* __restrict__ Rrow,
                                                  float* __restrict__ out) {
    int row = blockIdx.x;           // NEW (sorted) index
    int lane = threadIdx.x;
    if (row == 0 && lane == 0) out[0] = 0.0f;  // for merge_kernel's atomicAdd
    int o = perm[row];              // old row
    float4 v = ((const float4*)(F + (size_t)o * D))[lane];
    ushort4 h, l;
    h.x = f2bf(v.x); l.x = f2bf(v.x - bf2f(h.x));
    h.y = f2bf(v.y); l.y = f2bf(v.y - bf2f(h.y));
    h.z = f2bf(v.z); l.z = f2bf(v.z - bf2f(h.z));
    h.w = f2bf(v.w); l.w = f2bf(v.w - bf2f(h.w));
    ((ushort4*)(Fhi + (size_t)row * D))[lane] = h;
    ((ushort4*)(Flo + (size_t)row * D))[lane] = l;
    float s = v.x * v.x + v.y * v.y + v.z * v.z + v.w * v.w;
#pragma unroll
    for (int off = 32; off > 0; off >>= 1) s += __shfl_down(s, off, 64);
    if (lane == 0) {
        sq[row] = s;
        Rrow[row] = -SCALEF * sqrtf(2.0f * s);  // per-row exp reference shift
    }
}

// ---------------- Kernel 2: fused GEMM + online masked-topk-LSE ----------------
// Block: 64 rows (i) x 256 cols (j), 256 threads. Gram tile TRANSPOSED.
// LDST=40 (80 B): rows 16B-aligned (LDST=34 regressed 1.7x: misaligned splits).
//
// REGISTER-BUDGET HISTORY (hard-won): (256,4) pins arch-VGPR at 64; R3's
// epilogue fits EXACTLY and every growth (R5 prefetch, R6 sum-trick, R7
// fast path) SPILLED (FETCH/WRITE x2-4). At (256,3) the budget is ~168:
// R8 (fast path, 76 regs) ran spill-free, and the R5-style REGISTER PREFETCH
// (+24 regs, ~100 total) becomes affordable -- it moves staging-load latency
// off the critical path (loads for step t+1 issue before step t's
// ds_read+MFMA phase, so the ds_write's vmcnt wait is pre-covered).
#define LDST 40

// Epilogue for one finished 128(j) x (wave-tile) accumulation.
// Keys base-2: k2 = (x-R)*log2e = fma(d, -SCALE*log2e, -R*log2e); exp
// contribution = one v_exp_f32. Rows are camera-sorted: tile [jb, jb+16) is
// ALL-INTER for every row of this wave iff it misses [uLo, uHi) (union of the
// wave's rows' camera ranges; SGPR-resident) -> fast path: no camid load, no
// cmp/cndmask, no sIa, no tI insert. ~85% of tiles. Diagonal tiles are always
// same-camera, hence never fast -> fast path is HD-independent.
template <bool HD>
__device__ __forceinline__ void epi_tile(
    const floatx4 (&acc)[4][2], int j0, int wr, int quad, int uLo, int uHi,
    const float (&si)[2], const float (&nR2)[2], const int (&ci4)[2], const int (&ig)[2],
    const float* __restrict__ sq, const int* __restrict__ scam,
    float (&tI)[2][LI], float (&tX)[2][LX], float (&sIa)[2], float (&sXa)[2]) {
    const float C1 = -SCALEF * LOG2EF;
#pragma unroll
    for (int mi = 0; mi < 4; ++mi) {
        int jb = j0 + wr * 64 + mi * 16;   // wave-uniform tile base
        int jg0 = jb + quad * 4;
        float4 sj4 = *(const float4*)(sq + jg0);
        const float* sjp = (const float*)&sj4;
        bool fastTile = (uHi <= jb) || (uLo >= jb + 16);  // wave-uniform (SGPR)
        if (fastTile) {
#pragma unroll
            for (int ni = 0; ni < 2; ++ni) {
                float sie = si[ni] + EPSF;
#pragma unroll
                for (int r = 0; r < 4; ++r) {
                    float d2 = sie + sjp[r] - 2.0f * acc[mi][ni][r];
                    float d = sqrtf(fmaxf(d2, 1e-12f));
                    float k = fmaf(d, C1, nR2[ni]);
                    sXa[ni] += fast_exp2(k);
                    insert_desc<LX>(tX[ni], k);
                }
            }
        } else {
            int4 cj4 = *(const int4*)(scam + jg0);
            const int* cjp = (const int*)&cj4;
#pragma unroll
            for (int ni = 0; ni < 2; ++ni) {
                int dd = jg0 - ig[ni];  // diagonal at r == -dd
                float sie = si[ni] + EPSF;
#pragma unroll
                for (int r = 0; r < 4; ++r) {
                    float d2 = sie + sjp[r] - 2.0f * acc[mi][ni][r];
                    float d = sqrtf(fmaxf(d2, 1e-12f));
                    float k = fmaf(d, C1, nR2[ni]);
                    float e = fast_exp2(k);
                    bool ii = (cjp[r] == ci4[ni]);
                    bool okI = HD ? (ii && ((dd + r) != 0)) : ii;
                    sIa[ni] += okI ? e : 0.0f;
                    sXa[ni] += ii ? 0.0f : e;
                    insert_desc<LI>(tI[ni], okI ? k : -INFINITY);
                    insert_desc<LX>(tX[ni], ii ? -INFINITY : k);
                }
            }
        }
    }
}

__global__ __launch_bounds__(256, 3) void fused_kernel(
    const ushort_t* __restrict__ Fhi, const ushort_t* __restrict__ Flo,
    const float* __restrict__ sq, const float* __restrict__ Rrow,
    const int* __restrict__ scam, const int* __restrict__ camLoC,
    const int* __restrict__ camHiC,
    float4* __restrict__ partA, float4* __restrict__ partB, float4* __restrict__ partC) {
    // regions: Ahi[128], Alo[128], Bhi[64], Blo[64] rows of LDST shorts = 30720 B
    __shared__ ushort_t lds[(128 + 128 + 64 + 64) * LDST];
    ushort_t* ldsAh = lds;
    ushort_t* ldsAl = lds + 128 * LDST;
    ushort_t* ldsBh = lds + 256 * LDST;
    ushort_t* ldsBl = lds + 320 * LDST;

    int tid = threadIdx.x;
    int wave = tid >> 6, lane = tid & 63;
    int wr = wave >> 1, wc = wave & 1;   // wr: j-half of 128-subtile, wc: i-half of 64
    int lane15 = lane & 15, quad = lane >> 4;
    int cid = blockIdx.x, sid = blockIdx.y;
    int i0 = sid * 64, j00 = cid * 256;

    // per-lane row info (2 rows: ni = 0..1)
    float si[2], nR2[2];
    int ci4[2], ig[2];
#pragma unroll
    for (int ni = 0; ni < 2; ++ni) {
        int i = i0 + wc * 32 + ni * 16 + lane15;
        ig[ni] = i;
        si[ni] = sq[i];
        nR2[ni] = -Rrow[i] * LOG2EF;
        ci4[ni] = scam[i];
    }
    // wave-uniform camera-range union of this wave's 32 rows (sorted cams ->
    // union = [start(cam(firstRow)), end(cam(lastRow))). SGPR-resident.
    int rA = i0 + wc * 32;
    int uLo = __builtin_amdgcn_readfirstlane(camLoC[scam[rA]]);
    int uHi = __builtin_amdgcn_readfirstlane(camHiC[scam[rA + 31]]);

    float tI[2][LI], tX[2][LX], sIa[2], sXa[2];
#pragma unroll
    for (int ni = 0; ni < 2; ++ni) {
#pragma unroll
        for (int q = 0; q < LI; ++q) tI[ni][q] = -INFINITY;
#pragma unroll
        for (int q = 0; q < LX; ++q) tX[ni][q] = -INFINITY;
        sIa[ni] = 0.0f; sXa[ni] = 0.0f;
    }

    // staging maps: A-side 128 rows x 2 halves (16B each); B-side 64 rows x 4 quarters
    int srowA = tid >> 1, shalf = tid & 1;
    int srowB = tid >> 2, squart = tid & 3;
    const ushort_t* gBh = Fhi + (size_t)(i0 + srowB) * D + squart * 8;
    const ushort_t* gBl = Flo + (size_t)(i0 + srowB) * D + squart * 8;
    ushort_t* sdstAh = ldsAh + srowA * LDST + shalf * 16;
    ushort_t* sdstAl = ldsAl + srowA * LDST + shalf * 16;
    ushort_t* sdstBh = ldsBh + srowB * LDST + squart * 8;
    ushort_t* sdstBl = ldsBl + srowB * LDST + squart * 8;

    // prefetch registers for the CURRENT K-step (loaded one step ahead)
    short8 ra[2], rb[2], rc, rd;
    {
        const ushort_t* pAh = Fhi + (size_t)(j00 + srowA) * D + shalf * 16;
        const ushort_t* pAl = Flo + (size_t)(j00 + srowA) * D + shalf * 16;
#pragma unroll
        for (int q = 0; q < 2; ++q) {
            ra[q] = *(const short8*)(pAh + q * 8);
            rb[q] = *(const short8*)(pAl + q * 8);
        }
        rc = *(const short8*)(gBh);
        rd = *(const short8*)(gBl);
    }

#pragma unroll 1
    for (int jt = 0; jt < 2; ++jt) {
        int j0 = j00 + jt * 128;
        const ushort_t* gAh = Fhi + (size_t)(j0 + srowA) * D + shalf * 16;
        const ushort_t* gAl = Flo + (size_t)(j0 + srowA) * D + shalf * 16;
        floatx4 acc[4][2] = {};

#pragma unroll 1
        for (int kt = 0; kt < 8; ++kt) {
            __syncthreads();   // previous step's ds_reads done before overwrite
#pragma unroll
            for (int q = 0; q < 2; ++q) {
                *(short8*)(sdstAh + q * 8) = ra[q];
                *(short8*)(sdstAl + q * 8) = rb[q];
            }
            *(short8*)(sdstBh) = rc;
            *(short8*)(sdstBl) = rd;
            __syncthreads();

            // prefetch NEXT step's chunks: issued before the ds_read+MFMA
            // phase, so their latency hides under ~350 cycles of compute.
            if (kt < 7) {
                int koff = (kt + 1) * 32;
#pragma unroll
                for (int q = 0; q < 2; ++q) {
                    ra[q] = *(const short8*)(gAh + koff + q * 8);
                    rb[q] = *(const short8*)(gAl + koff + q * 8);
                }
                rc = *(const short8*)(gBh + koff);
                rd = *(const short8*)(gBl + koff);
            } else if (jt == 0) {  // first chunk of jt=1
                const ushort_t* nAh = gAh + (size_t)128 * D;
                const ushort_t* nAl = gAl + (size_t)128 * D;
#pragma unroll
                for (int q = 0; q < 2; ++q) {
                    ra[q] = *(const short8*)(nAh + q * 8);
                    rb[q] = *(const short8*)(nAl + q * 8);
                }
                rc = *(const short8*)(gBh);
                rd = *(const short8*)(gBl);
            }

            int eoff = quad * 8;
            short8 ahi[4], alo[4];
#pragma unroll
            for (int mi = 0; mi < 4; ++mi) {
                int r = wr * 64 + mi * 16 + lane15;  // j-side rows [0,128)
                ahi[mi] = *(const short8*)(ldsAh + r * LDST + eoff);
                alo[mi] = *(const short8*)(ldsAl + r * LDST + eoff);
            }
#pragma unroll
            for (int ni = 0; ni < 2; ++ni) {
                int r = wc * 32 + ni * 16 + lane15;  // i-side rows [0,64)
                short8 bhi = *(const short8*)(ldsBh + r * LDST + eoff);
                short8 blo = *(const short8*)(ldsBl + r * LDST + eoff);
#pragma unroll
                for (int mi = 0; mi < 4; ++mi) {
                    acc[mi][ni] = __builtin_amdgcn_mfma_f32_16x16x32_bf16(ahi[mi], bhi, acc[mi][ni], 0, 0, 0);
                    acc[mi][ni] = __builtin_amdgcn_mfma_f32_16x16x32_bf16(ahi[mi], blo, acc[mi][ni], 0, 0, 0);
                    acc[mi][ni] = __builtin_amdgcn_mfma_f32_16x16x32_bf16(alo[mi], bhi, acc[mi][ni], 0, 0, 0);
                }
            }
        }

        // diagonal (self-pairs stay on the diagonal under symmetric permute):
        // i-range [sid*64,+64) meets j-subtile iff cid==sid>>2 && jt==(sid>>1)&1
        if (cid == (sid >> 2) && jt == ((sid >> 1) & 1))
            epi_tile<true>(acc, j0, wr, quad, uLo, uHi, si, nR2, ci4, ig, sq, scam, tI, tX, sIa, sXa);
        else
            epi_tile<false>(acc, j0, wr, quad, uLo, uHi, si, nR2, ci4, ig, sq, scam, tI, tX, sIa, sXa);
    }

    // merge across the 4 quads sharing each row (butterfly, offsets 16 & 32).
    // CRITICAL: snapshot ALL partner values BEFORE mutating own lists.
#pragma unroll
    for (int off = 16; off <= 32; off <<= 1) {
#pragma unroll
        for (int ni = 0; ni < 2; ++ni) {
            sIa[ni] += __shfl_xor(sIa[ni], off, 64);
            sXa[ni] += __shfl_xor(sXa[ni], off, 64);
            float oI[LI], oX[LX];
#pragma unroll
            for (int q = 0; q < LI; ++q) oI[q] = __shfl_xor(tI[ni][q], off, 64);
#pragma unroll
            for (int q = 0; q < LX; ++q) oX[q] = __shfl_xor(tX[ni][q], off, 64);
#pragma unroll
            for (int q = 0; q < LI; ++q) insert_desc<LI>(tI[ni], oI[q]);
#pragma unroll
            for (int q = 0; q < LX; ++q) insert_desc<LX>(tX[ni], oX[q]);
        }
    }

    if (quad == 0) {
        int p = cid * 2 + wr;
#pragma unroll
        for (int ni = 0; ni < 2; ++ni) {
            size_t idx = (size_t)p * N + ig[ni];
            partA[idx] = make_float4(tI[ni][0], tI[ni][1], tI[ni][2], sIa[ni]);
            partB[idx] = make_float4(tX[ni][0], tX[ni][1], tX[ni][2], tX[ni][3]);
            partC[idx] = make_float4(tX[ni][4], tX[ni][5], sXa[ni], 0.0f);
        }
    }
}

// ---------------- Kernel 3: merge partials -> per-row loss -> global sum ----------------
// Stored list values are BASE-2 keys k2 = (x - R)*log2e; exp contribution is
// exp2(k2) = exp(x - R); natural log re-enters via *LN2 where needed.
// Block-reduces 256 rows and atomicAdds the scaled partial into out[0]
// (zeroed by prep_kernel earlier in the stream).
__global__ __launch_bounds__(256) void merge_kernel(const float4* __restrict__ partA,
                                                    const float4* __restrict__ partB,
                                                    const float4* __restrict__ partC,
                                                    const float* __restrict__ Rrow,
                                                    float* __restrict__ out) {
    int tid = threadIdx.x;
    int row = blockIdx.x * 256 + tid;
    float mI[LI] = {-INFINITY, -INFINITY, -INFINITY};
    float mX[LX] = {-INFINITY, -INFINITY, -INFINITY, -INFINITY, -INFINITY, -INFINITY};
    float SI = 0.0f, SX = 0.0f;
#pragma unroll 4
    for (int p = 0; p < PPARTS; ++p) {
        size_t idx = (size_t)p * N + row;
        float4 a = partA[idx];
        float4 b = partB[idx];
        float4 c = partC[idx];
        insert_desc<LI>(mI, a.x); insert_desc<LI>(mI, a.y); insert_desc<LI>(mI, a.z);
        SI += a.w;
        insert_desc<LX>(mX, b.x); insert_desc<LX>(mX, b.y);
        insert_desc<LX>(mX, b.z); insert_desc<LX>(mX, b.w);
        insert_desc<LX>(mX, c.x); insert_desc<LX>(mX, c.y);
        SX += c.z;
    }
    float R = Rrow[row];
    // intra: exclude diag (by construction) + top-3 values
    float subI = fast_exp2(mI[0]) + fast_exp2(mI[1]) + fast_exp2(mI[2]);
    float restI = fmaxf(SI - subI, 1e-37f);
    float yI = R + logf(restI);
    float hI = fmaxf(yI + SCALEF * sqrtf(EPSF) + MARGIN_INTRA, 0.0f);  // -x0 = +10*sqrt(eps)
    // inter: exclude top-6; -x0 + yX = logf(restX) - mX[0]*ln2  (R cancels)
    float subX = fast_exp2(mX[0]) + fast_exp2(mX[1]) + fast_exp2(mX[2]) +
                 fast_exp2(mX[3]) + fast_exp2(mX[4]) + fast_exp2(mX[5]);
    float restX = fmaxf(SX - subX, 1e-37f);
    float hX = fmaxf(logf(restX) - mX[0] * LN2F + MARGIN_INTER, 0.0f);
    float l = hI + 0.5f * hX;

    __shared__ float sbuf[256];
    sbuf[tid] = l;
    __syncthreads();
    for (int stride = 128; stride > 0; stride >>= 1) {
        if (tid < stride) sbuf[tid] += sbuf[tid + stride];
        __syncthreads();
    }
    if (tid == 0) atomicAdd(out, sbuf[0] * (1.0f / (float)N));
}

extern "C" void kernel_launch(void* const* d_in, const int* in_sizes, int n_in,
                              void* d_out, int out_size, void* d_ws, size_t ws_size,
                              hipStream_t stream) {
    const float* F = (const float*)d_in[0];
    const int* camid = (const int*)d_in[1];
    float* out = (float*)d_out;
    char* ws = (char*)d_ws;

    ushort_t* Fhi = (ushort_t*)ws;                               // 2 MB
    ushort_t* Flo = Fhi + (size_t)N * D;                         // 2 MB
    float* sq = (float*)(ws + 2 * (size_t)N * D * 2);            // 16 KB
    float* Rrow = sq + N;                                        // 16 KB
    float* rowloss = Rrow + N;                                   // 16 KB (unused, kept for layout)
    (void)rowloss;
    float4* partA = (float4*)(ws + 2 * (size_t)N * D * 2 + 3 * N * 4);  // 2 MB each
    float4* partB = partA + (size_t)PPARTS * N;
    float4* partC = partB + (size_t)PPARTS * N;
    int* perm = (int*)(partC + (size_t)PPARTS * N);              // 16 KB
    int* sortedCam = perm + N;                                   // 16 KB
    int* camLoC = sortedCam + N;                                 // 32 B
    int* camHiC = camLoC + NCAM;                                 // 32 B

    sort_kernel<<<1, 256, 0, stream>>>(camid, perm, sortedCam, camLoC, camHiC);
    prep_kernel<<<N, 64, 0, stream>>>(F, perm, Fhi, Flo, sq, Rrow, out);
    fused_kernel<<<dim3(NCHUNK, NSTRIP), 256, 0, stream>>>(Fhi, Flo, sq, Rrow, sortedCam,
                                                           camLoC, camHiC,
                                                           partA, partB, partC);
    merge_kernel<<<N / 256, 256, 0, stream>>>(partA, partB, partC, Rrow, out);
}

// Round 10
// 131.424 us; speedup vs baseline: 1.0458x; 1.0458x over previous
//
#include <hip/hip_runtime.h>
#include <hip/hip_bf16.h>
#include <math.h>

#define N 4096
#define D 256
#define NCAM 8
#define SCALEF 10.0f
#define EPSF 1e-5f
#define MARGIN_INTRA 40.0f
#define MARGIN_INTER 6.0f
// reference excludes sorted_intra[0:4] = diagonal + top-3 non-diag, sorted_inter[0:6]
#define LI 3
#define LX 6
#define NCHUNK 16   // j-chunks of 256
#define NSTRIP 64   // i-strips of 64 -> 1024 blocks = 4 blocks/CU
#define PPARTS (NCHUNK * 2)  // partial per (chunk, wr)

#define LOG2EF 1.44269504f
#define LN2F 0.69314718f

typedef unsigned short ushort_t;
typedef __attribute__((ext_vector_type(8))) short short8;
typedef __attribute__((ext_vector_type(4))) float floatx4;

__device__ __forceinline__ ushort_t f2bf(float x) {
    __hip_bfloat16 h = __float2bfloat16(x);
    return *reinterpret_cast<ushort_t*>(&h);
}
__device__ __forceinline__ float bf2f(ushort_t u) {
    __hip_bfloat16 h = *reinterpret_cast<__hip_bfloat16*>(&u);
    return __bfloat162float(h);
}

__device__ __forceinline__ float fast_exp2(float x) {
#if __has_builtin(__builtin_amdgcn_exp2f)
    return __builtin_amdgcn_exp2f(x);
#else
    return exp2f(x);
#endif
}

// Insert v into descending-sorted list t[0..L-1], keep top L.
// t0' = max(t0,v); tq' = med3(t[q-1], t[q], v)  -> L ops, depth-1 chain.
template <int L>
__device__ __forceinline__ void insert_desc(float (&t)[L], float v) {
    float top = fmaxf(t[0], v);
#pragma unroll
    for (int q = L - 1; q >= 1; --q)
        t[q] = __builtin_amdgcn_fmed3f(t[q - 1], t[q], v);
    t[0] = top;
}

// ---------------- Kernel 0: counting sort of rows by camid ----------------
// Loss is permutation-invariant (per-row loss summed over rows; each row's
// distance SET is unchanged); sorting makes each camera's columns one
// contiguous range -> wave-uniform intra/inter classification in the fused
// epilogue. Within-camera order is arbitrary (only reorders fp sums).
__global__ __launch_bounds__(256) void sort_kernel(const int* __restrict__ camid,
                                                   int* __restrict__ perm,
                                                   int* __restrict__ sortedCam,
                                                   int* __restrict__ camLoC,
                                                   int* __restrict__ camHiC) {
    __shared__ int hist[NCAM], cursor[NCAM];
    int tid = threadIdx.x;
    if (tid < NCAM) hist[tid] = 0;
    __syncthreads();
    int ids[16];
#pragma unroll
    for (int q = 0; q < 16; ++q) {
        ids[q] = camid[tid * 16 + q];
        atomicAdd(&hist[ids[q]], 1);
    }
    __syncthreads();
    if (tid == 0) {
        int acc = 0;
        for (int c = 0; c < NCAM; ++c) {
            cursor[c] = acc;
            camLoC[c] = acc;
            acc += hist[c];
            camHiC[c] = acc;
        }
    }
    __syncthreads();
#pragma unroll
    for (int q = 0; q < 16; ++q) {
        int o = tid * 16 + q;
        int pos = atomicAdd(&cursor[ids[q]], 1);
        perm[pos] = o;
        sortedCam[pos] = ids[q];
    }
}

// ---------------- Kernel 1: per-row sq, R, bf16 hi/lo split (gathered) ----------------
__global__ __launch_bounds__(64) void prep_kernel(const float* __restrict__ F,
                                                  const int* __restrict__ perm,
                                                  ushort_t* __restrict__ Fhi,
                                                  ushort_t* __restrict__ Flo,
                                                  float* __restrict__ sq,
                                                  float* __restrict__ Rrow,
                                                  float* __restrict__ out) {
    int row = blockIdx.x;           // NEW (sorted) index
    int lane = threadIdx.x;
    if (row == 0 && lane == 0) out[0] = 0.0f;  // for merge_kernel's atomicAdd
    int o = perm[row];              // old row
    float4 v = ((const float4*)(F + (size_t)o * D))[lane];
    ushort4 h, l;
    h.x = f2bf(v.x); l.x = f2bf(v.x - bf2f(h.x));
    h.y = f2bf(v.y); l.y = f2bf(v.y - bf2f(h.y));
    h.z = f2bf(v.z); l.z = f2bf(v.z - bf2f(h.z));
    h.w = f2bf(v.w); l.w = f2bf(v.w - bf2f(h.w));
    ((ushort4*)(Fhi + (size_t)row * D))[lane] = h;
    ((ushort4*)(Flo + (size_t)row * D))[lane] = l;
    float s = v.x * v.x + v.y * v.y + v.z * v.z + v.w * v.w;
#pragma unroll
    for (int off = 32; off > 0; off >>= 1) s += __shfl_down(s, off, 64);
    if (lane == 0) {
        sq[row] = s;
        Rrow[row] = -SCALEF * sqrtf(2.0f * s);  // per-row exp reference shift
    }
}

// ---------------- Kernel 2: fused GEMM + online masked-topk-LSE ----------------
// Block: 64 rows (i) x 256 cols (j), 256 threads. Gram tile TRANSPOSED.
// LDST=40 (80 B): rows 16B-aligned (LDST=34 regressed 1.7x: misaligned splits).
//
// REGISTER-BUDGET HISTORY (hard-won): (256,4) pins arch-VGPR at 64; the R3
// epilogue fits EXACTLY. Register prefetch across the barrier pair spilled in
// ALL THREE attempts (R1/R5/R9 -- even at the (256,3) budget): that line is
// dead. The R7/R8 per-tile fast/slow branch also spilled at (256,4) (both
// paths' state live inside the mi-loop). THIS version hoists the branch to
// the wave's whole 64-wide j-span: two SEPARATE whole-tile epilogues, so
// peak pressure = max(paths) = the proven R3 path. Fast path (~85% of spans,
// camera-sorted) is a strict register/instruction subset.
#define LDST 40

// FAST epilogue: the wave's 64-wide j-span is entirely inter-camera for all
// of its 32 rows. No camid load, no cmp/cndmask, no tI/sIa, plain sums.
__device__ __forceinline__ void epi_fast(
    const floatx4 (&acc)[4][2], int j0, int wr, int quad,
    const float (&si)[2], const float (&nR2)[2],
    const float* __restrict__ sq,
    float (&tX)[2][LX], float (&sXa)[2]) {
    const float C1 = -SCALEF * LOG2EF;
#pragma unroll
    for (int mi = 0; mi < 4; ++mi) {
        int jg0 = j0 + wr * 64 + mi * 16 + quad * 4;
        float4 sj4 = *(const float4*)(sq + jg0);
        const float* sjp = (const float*)&sj4;
#pragma unroll
        for (int ni = 0; ni < 2; ++ni) {
            float sie = si[ni] + EPSF;
#pragma unroll
            for (int r = 0; r < 4; ++r) {
                float d2 = sie + sjp[r] - 2.0f * acc[mi][ni][r];
                float d = sqrtf(fmaxf(d2, 1e-12f));
                float k = fmaf(d, C1, nR2[ni]);  // (x - R) * log2e
                sXa[ni] += fast_exp2(k);
                insert_desc<LX>(tX[ni], k);
            }
        }
    }
}

// FULL epilogue: bit-identical to the proven R3 path (fits the 64-reg budget).
// Keys base-2: k2 = (x-R)*log2e; exp contribution = one v_exp_f32.
template <bool HD>
__device__ __forceinline__ void epi_full(
    const floatx4 (&acc)[4][2], int j0, int wr, int quad,
    const float (&si)[2], const float (&nR2)[2], const int (&ci4)[2], const int (&ig)[2],
    const float* __restrict__ sq, const int* __restrict__ scam,
    float (&tI)[2][LI], float (&tX)[2][LX], float (&sIa)[2], float (&sXa)[2]) {
    const float C1 = -SCALEF * LOG2EF;
#pragma unroll
    for (int mi = 0; mi < 4; ++mi) {
        int jg0 = j0 + wr * 64 + mi * 16 + quad * 4;
        float4 sj4 = *(const float4*)(sq + jg0);
        int4 cj4 = *(const int4*)(scam + jg0);
        const float* sjp = (const float*)&sj4;
        const int* cjp = (const int*)&cj4;
#pragma unroll
        for (int ni = 0; ni < 2; ++ni) {
            int dd = jg0 - ig[ni];  // diagonal at r == -dd
            float sie = si[ni] + EPSF;
#pragma unroll
            for (int r = 0; r < 4; ++r) {
                float d2 = sie + sjp[r] - 2.0f * acc[mi][ni][r];
                float d = sqrtf(fmaxf(d2, 1e-12f));
                float k = fmaf(d, C1, nR2[ni]);  // (x - R) * log2e
                float e = fast_exp2(k);
                bool ii = (cjp[r] == ci4[ni]);
                bool okI = HD ? (ii && ((dd + r) != 0)) : ii;
                sIa[ni] += okI ? e : 0.0f;
                sXa[ni] += ii ? 0.0f : e;
                insert_desc<LI>(tI[ni], okI ? k : -INFINITY);
                insert_desc<LX>(tX[ni], ii ? -INFINITY : k);
            }
        }
    }
}

__global__ __launch_bounds__(256, 4) void fused_kernel(
    const ushort_t* __restrict__ Fhi, const ushort_t* __restrict__ Flo,
    const float* __restrict__ sq, const float* __restrict__ Rrow,
    const int* __restrict__ scam, const int* __restrict__ camLoC,
    const int* __restrict__ camHiC,
    float4* __restrict__ partA, float4* __restrict__ partB, float4* __restrict__ partC) {
    // regions: Ahi[128], Alo[128], Bhi[64], Blo[64] rows of LDST shorts = 30720 B
    __shared__ ushort_t lds[(128 + 128 + 64 + 64) * LDST];
    ushort_t* ldsAh = lds;
    ushort_t* ldsAl = lds + 128 * LDST;
    ushort_t* ldsBh = lds + 256 * LDST;
    ushort_t* ldsBl = lds + 320 * LDST;

    int tid = threadIdx.x;
    int wave = tid >> 6, lane = tid & 63;
    int wr = wave >> 1, wc = wave & 1;   // wr: j-half of 128-subtile, wc: i-half of 64
    int lane15 = lane & 15, quad = lane >> 4;
    int cid = blockIdx.x, sid = blockIdx.y;
    int i0 = sid * 64, j00 = cid * 256;

    // per-lane row info (2 rows: ni = 0..1)
    float si[2], nR2[2];
    int ci4[2], ig[2];
#pragma unroll
    for (int ni = 0; ni < 2; ++ni) {
        int i = i0 + wc * 32 + ni * 16 + lane15;
        ig[ni] = i;
        si[ni] = sq[i];
        nR2[ni] = -Rrow[i] * LOG2EF;
        ci4[ni] = scam[i];
    }
    // wave-uniform camera-range union of this wave's 32 rows (sorted cams ->
    // union = [start(cam(firstRow)), end(cam(lastRow))). SGPR-resident.
    int rA = i0 + wc * 32;
    int uLo = __builtin_amdgcn_readfirstlane(camLoC[scam[rA]]);
    int uHi = __builtin_amdgcn_readfirstlane(camHiC[scam[rA + 31]]);

    float tI[2][LI], tX[2][LX], sIa[2], sXa[2];
#pragma unroll
    for (int ni = 0; ni < 2; ++ni) {
#pragma unroll
        for (int q = 0; q < LI; ++q) tI[ni][q] = -INFINITY;
#pragma unroll
        for (int q = 0; q < LX; ++q) tX[ni][q] = -INFINITY;
        sIa[ni] = 0.0f; sXa[ni] = 0.0f;
    }

    // staging maps: A-side 128 rows x 2 halves (16B each); B-side 64 rows x 4 quarters
    int srowA = tid >> 1, shalf = tid & 1;
    int srowB = tid >> 2, squart = tid & 3;
    const ushort_t* gBh = Fhi + (size_t)(i0 + srowB) * D + squart * 8;
    const ushort_t* gBl = Flo + (size_t)(i0 + srowB) * D + squart * 8;
    ushort_t* sdstAh = ldsAh + srowA * LDST + shalf * 16;
    ushort_t* sdstAl = ldsAl + srowA * LDST + shalf * 16;
    ushort_t* sdstBh = ldsBh + srowB * LDST + squart * 8;
    ushort_t* sdstBl = ldsBl + srowB * LDST + squart * 8;

#pragma unroll 1
    for (int jt = 0; jt < 2; ++jt) {
        int j0 = j00 + jt * 128;
        const ushort_t* gAh = Fhi + (size_t)(j0 + srowA) * D + shalf * 16;
        const ushort_t* gAl = Flo + (size_t)(j0 + srowA) * D + shalf * 16;
        floatx4 acc[4][2] = {};

#pragma unroll 1
        for (int kt = 0; kt < 8; ++kt) {
            int koff = kt * 32;
            short8 ra[2], rb[2], rc, rd;
#pragma unroll
            for (int q = 0; q < 2; ++q) {
                ra[q] = *(const short8*)(gAh + koff + q * 8);
                rb[q] = *(const short8*)(gAl + koff + q * 8);
            }
            rc = *(const short8*)(gBh + koff);
            rd = *(const short8*)(gBl + koff);
            __syncthreads();
#pragma unroll
            for (int q = 0; q < 2; ++q) {
                *(short8*)(sdstAh + q * 8) = ra[q];
                *(short8*)(sdstAl + q * 8) = rb[q];
            }
            *(short8*)(sdstBh) = rc;
            *(short8*)(sdstBl) = rd;
            __syncthreads();

            int eoff = quad * 8;
            short8 ahi[4], alo[4];
#pragma unroll
            for (int mi = 0; mi < 4; ++mi) {
                int r = wr * 64 + mi * 16 + lane15;  // j-side rows [0,128)
                ahi[mi] = *(const short8*)(ldsAh + r * LDST + eoff);
                alo[mi] = *(const short8*)(ldsAl + r * LDST + eoff);
            }
#pragma unroll
            for (int ni = 0; ni < 2; ++ni) {
                int r = wc * 32 + ni * 16 + lane15;  // i-side rows [0,64)
                short8 bhi = *(const short8*)(ldsBh + r * LDST + eoff);
                short8 blo = *(const short8*)(ldsBl + r * LDST + eoff);
#pragma unroll
                for (int mi = 0; mi < 4; ++mi) {
                    acc[mi][ni] = __builtin_amdgcn_mfma_f32_16x16x32_bf16(ahi[mi], bhi, acc[mi][ni], 0, 0, 0);
                    acc[mi][ni] = __builtin_amdgcn_mfma_f32_16x16x32_bf16(ahi[mi], blo, acc[mi][ni], 0, 0, 0);
                    acc[mi][ni] = __builtin_amdgcn_mfma_f32_16x16x32_bf16(alo[mi], bhi, acc[mi][ni], 0, 0, 0);
                }
            }
        }

        // Wave-level epilogue dispatch (branch is wave-uniform; no barriers
        // inside the epilogues, so divergence across waves is safe):
        // fast iff the wave's whole 64-wide j-span misses [uLo, uHi).
        // Diagonal cells are same-camera, so they can never be in a fast span;
        // HD (diag-containing block+jt) is only reachable via the full path.
        int jbw = j0 + wr * 64;
        bool fastJ = (uHi <= jbw) || (uLo >= jbw + 64);
        if (fastJ) {
            epi_fast(acc, j0, wr, quad, si, nR2, sq, tX, sXa);
        } else if (cid == (sid >> 2) && jt == ((sid >> 1) & 1)) {
            epi_full<true>(acc, j0, wr, quad, si, nR2, ci4, ig, sq, scam, tI, tX, sIa, sXa);
        } else {
            epi_full<false>(acc, j0, wr, quad, si, nR2, ci4, ig, sq, scam, tI, tX, sIa, sXa);
        }
    }

    // merge across the 4 quads sharing each row (butterfly, offsets 16 & 32).
    // CRITICAL: snapshot ALL partner values BEFORE mutating own lists.
#pragma unroll
    for (int off = 16; off <= 32; off <<= 1) {
#pragma unroll
        for (int ni = 0; ni < 2; ++ni) {
            sIa[ni] += __shfl_xor(sIa[ni], off, 64);
            sXa[ni] += __shfl_xor(sXa[ni], off, 64);
            float oI[LI], oX[LX];
#pragma unroll
            for (int q = 0; q < LI; ++q) oI[q] = __shfl_xor(tI[ni][q], off, 64);
#pragma unroll
            for (int q = 0; q < LX; ++q) oX[q] = __shfl_xor(tX[ni][q], off, 64);
#pragma unroll
            for (int q = 0; q < LI; ++q) insert_desc<LI>(tI[ni], oI[q]);
#pragma unroll
            for (int q = 0; q < LX; ++q) insert_desc<LX>(tX[ni], oX[q]);
        }
    }

    if (quad == 0) {
        int p = cid * 2 + wr;
#pragma unroll
        for (int ni = 0; ni < 2; ++ni) {
            size_t idx = (size_t)p * N + ig[ni];
            partA[idx] = make_float4(tI[ni][0], tI[ni][1], tI[ni][2], sIa[ni]);
            partB[idx] = make_float4(tX[ni][0], tX[ni][1], tX[ni][2], tX[ni][3]);
            partC[idx] = make_float4(tX[ni][4], tX[ni][5], sXa[ni], 0.0f);
        }
    }
}

// ---------------- Kernel 3: merge partials -> per-row loss -> global sum ----------------
// Stored list values are BASE-2 keys k2 = (x - R)*log2e; exp contribution is
// exp2(k2) = exp(x - R); natural log re-enters via *LN2 where needed.
// Block-reduces 256 rows and atomicAdds the scaled partial into out[0]
// (zeroed by prep_kernel earlier in the stream).
__global__ __launch_bounds__(256) void merge_kernel(const float4* __restrict__ partA,
                                                    const float4* __restrict__ partB,
                                                    const float4* __restrict__ partC,
                                                    const float* __restrict__ Rrow,
                                                    float* __restrict__ out) {
    int tid = threadIdx.x;
    int row = blockIdx.x * 256 + tid;
    float mI[LI] = {-INFINITY, -INFINITY, -INFINITY};
    float mX[LX] = {-INFINITY, -INFINITY, -INFINITY, -INFINITY, -INFINITY, -INFINITY};
    float SI = 0.0f, SX = 0.0f;
#pragma unroll 4
    for (int p = 0; p < PPARTS; ++p) {
        size_t idx = (size_t)p * N + row;
        float4 a = partA[idx];
        float4 b = partB[idx];
        float4 c = partC[idx];
        insert_desc<LI>(mI, a.x); insert_desc<LI>(mI, a.y); insert_desc<LI>(mI, a.z);
        SI += a.w;
        insert_desc<LX>(mX, b.x); insert_desc<LX>(mX, b.y);
        insert_desc<LX>(mX, b.z); insert_desc<LX>(mX, b.w);
        insert_desc<LX>(mX, c.x); insert_desc<LX>(mX, c.y);
        SX += c.z;
    }
    float R = Rrow[row];
    // intra: exclude diag (by construction) + top-3 values
    float subI = fast_exp2(mI[0]) + fast_exp2(mI[1]) + fast_exp2(mI[2]);
    float restI = fmaxf(SI - subI, 1e-37f);
    float yI = R + logf(restI);
    float hI = fmaxf(yI + SCALEF * sqrtf(EPSF) + MARGIN_INTRA, 0.0f);  // -x0 = +10*sqrt(eps)
    // inter: exclude top-6; -x0 + yX = logf(restX) - mX[0]*ln2  (R cancels)
    float subX = fast_exp2(mX[0]) + fast_exp2(mX[1]) + fast_exp2(mX[2]) +
                 fast_exp2(mX[3]) + fast_exp2(mX[4]) + fast_exp2(mX[5]);
    float restX = fmaxf(SX - subX, 1e-37f);
    float hX = fmaxf(logf(restX) - mX[0] * LN2F + MARGIN_INTER, 0.0f);
    float l = hI + 0.5f * hX;

    __shared__ float sbuf[256];
    sbuf[tid] = l;
    __syncthreads();
    for (int stride = 128; stride > 0; stride >>= 1) {
        if (tid < stride) sbuf[tid] += sbuf[tid + stride];
        __syncthreads();
    }
    if (tid == 0) atomicAdd(out, sbuf[0] * (1.0f / (float)N));
}

extern "C" void kernel_launch(void* const* d_in, const int* in_sizes, int n_in,
                              void* d_out, int out_size, void* d_ws, size_t ws_size,
                              hipStream_t stream) {
    const float* F = (const float*)d_in[0];
    const int* camid = (const int*)d_in[1];
    float* out = (float*)d_out;
    char* ws = (char*)d_ws;

    ushort_t* Fhi = (ushort_t*)ws;                               // 2 MB
    ushort_t* Flo = Fhi + (size_t)N * D;                         // 2 MB
    float* sq = (float*)(ws + 2 * (size_t)N * D * 2);            // 16 KB
    float* Rrow = sq + N;                                        // 16 KB
    float* rowloss = Rrow + N;                                   // 16 KB (unused, kept for layout)
    (void)rowloss;
    float4* partA = (float4*)(ws + 2 * (size_t)N * D * 2 + 3 * N * 4);  // 2 MB each
    float4* partB = partA + (size_t)PPARTS * N;
    float4* partC = partB + (size_t)PPARTS * N;
    int* perm = (int*)(partC + (size_t)PPARTS * N);              // 16 KB
    int* sortedCam = perm + N;                                   // 16 KB
    int* camLoC = sortedCam + N;                                 // 32 B
    int* camHiC = camLoC + NCAM;                                 // 32 B

    sort_kernel<<<1, 256, 0, stream>>>(camid, perm, sortedCam, camLoC, camHiC);
    prep_kernel<<<N, 64, 0, stream>>>(F, perm, Fhi, Flo, sq, Rrow, out);
    fused_kernel<<<dim3(NCHUNK, NSTRIP), 256, 0, stream>>>(Fhi, Flo, sq, Rrow, sortedCam,
                                                           camLoC, camHiC,
                                                           partA, partB, partC);
    merge_kernel<<<N / 256, 256, 0, stream>>>(partA, partB, partC, Rrow, out);
}